// Round 1
// baseline (1157.476 us; speedup 1.0000x reference)
//
#include <hip/hip_runtime.h>
#include <hip/hip_bf16.h>
#include <cmath>
#include <cstdint>

typedef __bf16 bf16_t;
typedef bf16_t bf16x8 __attribute__((ext_vector_type(8)));
typedef bf16_t bf16x4 __attribute__((ext_vector_type(4)));
typedef float  f32x4  __attribute__((ext_vector_type(4)));

#define VOCAB 32000
#define DDIM  1024
#define BATCH 4
#define SEQ   2048
#define MTOT  (BATCH*SEQ)                       // 8192
#define LOGITS_ELEMS (262144000LL)              // MTOT*VOCAB

// ---- ws layout (bytes) ----
#define WQKV_OFF 0LL                            // [3072][1024] bf16
#define WOUT_OFF 6291456LL                      // [32000][1024] bf16
#define X_OFF    71827456LL                     // [8192][1024] bf16 (reused as attn_out)
#define QKV_OFF  88604672LL                     // [8192][3072] bf16
#define VT_OFF   138936320LL                    // [4][1024][2048] bf16
#define ABF_OFF  155713536LL                    // [4][2048][2048] bf16
// END = 189267968 bytes required in ws

__device__ __forceinline__ void gl_lds16(const void* g, void* l) {
  __builtin_amdgcn_global_load_lds(
      (const __attribute__((address_space(1))) void*)g,
      (__attribute__((address_space(3))) void*)l, 16, 0, 0);
}

// ---------------- f32 -> bf16 convert (vectorized, grid-stride) ----------------
__global__ __launch_bounds__(256)
void cvt_bf16(const float* __restrict__ s, bf16_t* __restrict__ d, int n4) {
  int i = blockIdx.x * 256 + threadIdx.x;
  const int stride = gridDim.x * 256;
  for (; i < n4; i += stride) {
    float4 v = ((const float4*)s)[i];
    bf16x4 o;
    o[0] = (bf16_t)v.x; o[1] = (bf16_t)v.y; o[2] = (bf16_t)v.z; o[3] = (bf16_t)v.w;
    ((bf16x4*)d)[i] = o;
  }
}

// ---------------- embedding gather + cast ----------------
__global__ __launch_bounds__(256)
void gather_cast(const int* __restrict__ idx, const float* __restrict__ embed,
                 bf16_t* __restrict__ X) {
  const int m = blockIdx.x;
  const int row = idx[m];
  float4 v = ((const float4*)(embed + (long long)row * DDIM))[threadIdx.x];
  bf16x4 o;
  o[0] = (bf16_t)v.x; o[1] = (bf16_t)v.y; o[2] = (bf16_t)v.z; o[3] = (bf16_t)v.w;
  *(bf16x4*)(X + (long long)m * DDIM + threadIdx.x * 4) = o;
}

// ---------------- V transpose: QKV cols[2048..3071] -> Vt[b][d][s] ----------------
__global__ __launch_bounds__(256)
void transpose_v(const bf16_t* __restrict__ QKV, bf16_t* __restrict__ Vt) {
  __shared__ bf16_t tile[64][65];
  const int b = blockIdx.z;
  const int s0 = blockIdx.x * 64, d0 = blockIdx.y * 64;
  const int tx = threadIdx.x & 63, ty = threadIdx.x >> 6;
  #pragma unroll
  for (int i = ty; i < 64; i += 4)
    tile[i][tx] = QKV[((long long)b * SEQ + s0 + i) * 3072 + 2048 + d0 + tx];
  __syncthreads();
  #pragma unroll
  for (int i = ty; i < 64; i += 4)
    Vt[((long long)b * DDIM + d0 + i) * SEQ + s0 + tx] = tile[tx][i];
}

// ---------------- BT-GEMM: C[m,n] = sum_k A[m,k]*B[n,k] ----------------
// OMODE: 0 = bf16 out, 1 = f32 out, 2 = f32 out + bias
template<int OMODE, bool CSKIP, bool CTRIM>
__global__ __launch_bounds__(256)
void gemm_bt(const bf16_t* __restrict__ A, const bf16_t* __restrict__ B,
             void* __restrict__ Cv, const float* __restrict__ bias,
             int K, int lda, int ldb, int ldc,
             long long sA, long long sB, long long sC) {
  const int bn = blockIdx.x, bm = blockIdx.y, bz = blockIdx.z;
  if (CSKIP && bn > bm) return;

  __shared__ bf16_t As[128 * 32];
  __shared__ bf16_t Bs[128 * 32];

  const int t = threadIdx.x;
  const int lane = t & 63;
  const int w = t >> 6;
  const int wr = w >> 1, wc = w & 1;

  f32x4 acc[4][4];
  #pragma unroll
  for (int m = 0; m < 4; m++)
    #pragma unroll
    for (int n = 0; n < 4; n++)
      #pragma unroll
      for (int r = 0; r < 4; r++) acc[m][n][r] = 0.f;

  int kEnd = K;
  if (CTRIM) { int ke = (bm + 1) * 128; kEnd = ke < K ? ke : K; }

  const bf16_t* Ab = A + (long long)bz * sA + (long long)(bm * 128) * lda;
  const bf16_t* Bb = B + (long long)bz * sB + (long long)(bn * 128) * ldb;

  const int srow = t >> 2;
  const int scol = (t & 3) * 8;

  const int fr = lane & 15;
  const int fq = lane >> 4;
  const int aoff0 = (wr * 64 + fr) * 32 + fq * 8;
  const int boff0 = (wc * 64 + fr) * 32 + fq * 8;

  for (int k0 = 0; k0 < kEnd; k0 += 32) {
    gl_lds16(Ab + (long long)srow * lda + k0 + scol, &As[t * 8]);
    gl_lds16(Ab + (long long)(srow + 64) * lda + k0 + scol, &As[2048 + t * 8]);
    gl_lds16(Bb + (long long)srow * ldb + k0 + scol, &Bs[t * 8]);
    gl_lds16(Bb + (long long)(srow + 64) * ldb + k0 + scol, &Bs[2048 + t * 8]);
    __syncthreads();   // compiler emits vmcnt(0) drain before barrier

    bf16x8 af[4], bv[4];
    #pragma unroll
    for (int m = 0; m < 4; m++) af[m] = *(const bf16x8*)&As[aoff0 + m * 16 * 32];
    #pragma unroll
    for (int n = 0; n < 4; n++) bv[n] = *(const bf16x8*)&Bs[boff0 + n * 16 * 32];
    #pragma unroll
    for (int m = 0; m < 4; m++)
      #pragma unroll
      for (int n = 0; n < 4; n++)
        acc[m][n] = __builtin_amdgcn_mfma_f32_16x16x32_bf16(af[m], bv[n], acc[m][n], 0, 0, 0);
    __syncthreads();
  }

  const long long cb = (long long)bz * sC;
  const int row0 = bm * 128 + wr * 64 + fq * 4;
  const int col0 = bn * 128 + wc * 64 + fr;
  #pragma unroll
  for (int m = 0; m < 4; m++)
    #pragma unroll
    for (int n = 0; n < 4; n++) {
      const int col = col0 + n * 16;
      const float bvs = (OMODE == 2) ? bias[col] : 0.f;
      #pragma unroll
      for (int r = 0; r < 4; r++) {
        const int row = row0 + m * 16 + r;
        const float v = acc[m][n][r];
        if (OMODE == 0)
          ((bf16_t*)Cv)[cb + (long long)row * ldc + col] = (bf16_t)v;
        else
          ((float*)Cv)[cb + (long long)row * ldc + col] = v + bvs;
      }
    }
}

// ---------------- row softmax with causal mask ----------------
__device__ __forceinline__ float wred_max(float v) {
  #pragma unroll
  for (int o = 32; o; o >>= 1) v = fmaxf(v, __shfl_xor(v, o, 64));
  return v;
}
__device__ __forceinline__ float wred_sum(float v) {
  #pragma unroll
  for (int o = 32; o; o >>= 1) v += __shfl_xor(v, o, 64);
  return v;
}

__global__ __launch_bounds__(256)
void softmax_rows(const float* __restrict__ scores, float* __restrict__ Aout,
                  bf16_t* __restrict__ Abf) {
  const int m = blockIdx.x;          // 0..8191
  const int q = m & (SEQ - 1);
  const float* srow = scores + (long long)m * SEQ;
  const int t = threadIdx.x;
  const int base = t * 8;
  const float scale = 0.03125f;      // 1/sqrt(1024)

  float4 a = ((const float4*)srow)[t * 2];
  float4 b = ((const float4*)srow)[t * 2 + 1];
  float v[8] = {a.x, a.y, a.z, a.w, b.x, b.y, b.z, b.w};

  float mx = -INFINITY;
  #pragma unroll
  for (int i = 0; i < 8; i++) {
    v[i] = (base + i <= q) ? v[i] * scale : -INFINITY;
    mx = fmaxf(mx, v[i]);
  }
  __shared__ float redm[4], reds[4];
  const int lane = t & 63, w = t >> 6;
  float wm = wred_max(mx);
  if (lane == 0) redm[w] = wm;
  __syncthreads();
  mx = fmaxf(fmaxf(redm[0], redm[1]), fmaxf(redm[2], redm[3]));

  float e[8]; float s = 0.f;
  #pragma unroll
  for (int i = 0; i < 8; i++) {
    e[i] = (base + i <= q) ? __expf(v[i] - mx) : 0.f;
    s += e[i];
  }
  float wsu = wred_sum(s);
  if (lane == 0) reds[w] = wsu;
  __syncthreads();
  s = reds[0] + reds[1] + reds[2] + reds[3];
  const float inv = 1.f / s;

  float4 o0, o1; bf16x8 ob;
  float av[8];
  #pragma unroll
  for (int i = 0; i < 8; i++) { av[i] = e[i] * inv; ob[i] = (bf16_t)av[i]; }
  o0.x = av[0]; o0.y = av[1]; o0.z = av[2]; o0.w = av[3];
  o1.x = av[4]; o1.y = av[5]; o1.z = av[6]; o1.w = av[7];
  float* orow = Aout + (long long)m * SEQ;
  ((float4*)orow)[t * 2] = o0;
  ((float4*)orow)[t * 2 + 1] = o1;
  *(bf16x8*)(Abf + (long long)m * SEQ + base) = ob;
}

// ---------------- launch ----------------
extern "C" void kernel_launch(void* const* d_in, const int* in_sizes, int n_in,
                              void* d_out, int out_size, void* d_ws, size_t ws_size,
                              hipStream_t stream) {
  const int*   idx   = (const int*)d_in[0];
  const float* embed = (const float*)d_in[1];
  const float* Wq    = (const float*)d_in[2];
  const float* Wk    = (const float*)d_in[3];
  const float* Wv    = (const float*)d_in[4];
  const float* Wout  = (const float*)d_in[5];
  const float* bout  = (const float*)d_in[6];

  float* out = (float*)d_out;
  char*  ws  = (char*)d_ws;

  bf16_t* Wqkv  = (bf16_t*)(ws + WQKV_OFF);
  bf16_t* WoutB = (bf16_t*)(ws + WOUT_OFF);
  bf16_t* X     = (bf16_t*)(ws + X_OFF);
  bf16_t* QKV   = (bf16_t*)(ws + QKV_OFF);
  bf16_t* Vt    = (bf16_t*)(ws + VT_OFF);
  bf16_t* Abf   = (bf16_t*)(ws + ABF_OFF);
  bf16_t* AttnO = X;                       // X dead after QKV projection
  float*  scores = out;                    // scratch in (unwritten) logits region
  float*  Aout   = out + LOGITS_ELEMS;

  // weight converts
  cvt_bf16<<<1024, 256, 0, stream>>>(Wq, Wqkv,            262144);
  cvt_bf16<<<1024, 256, 0, stream>>>(Wk, Wqkv + 1048576,  262144);
  cvt_bf16<<<1024, 256, 0, stream>>>(Wv, Wqkv + 2097152,  262144);
  cvt_bf16<<<4096, 256, 0, stream>>>(Wout, WoutB,         8192000);

  // x = embed[idx] (bf16)
  gather_cast<<<8192, 256, 0, stream>>>(idx, embed, X);

  // QKV = X @ Wqkv^T  -> [8192][3072] bf16
  gemm_bt<0, false, false><<<dim3(24, 64, 1), 256, 0, stream>>>(
      X, Wqkv, QKV, nullptr, 1024, 1024, 1024, 3072, 0, 0, 0);

  // Vt[b][d][s]
  transpose_v<<<dim3(32, 16, 4), 256, 0, stream>>>(QKV, Vt);

  // scores[b][q][k] = Q.K^T (unscaled), lower-triangle tiles only
  gemm_bt<1, true, false><<<dim3(16, 16, 4), 256, 0, stream>>>(
      QKV, QKV + 1024, scores, nullptr, 1024, 3072, 3072, 2048,
      2048LL * 3072, 2048LL * 3072, 2048LL * 2048);

  // A = softmax(scores/32) with causal mask; writes f32 to d_out + bf16 to ws
  softmax_rows<<<8192, 256, 0, stream>>>(scores, Aout, Abf);

  // attn_out = A @ V   (K trimmed to causal extent)
  gemm_bt<0, false, true><<<dim3(8, 16, 4), 256, 0, stream>>>(
      Abf, Vt, AttnO, nullptr, 2048, 2048, 2048, 1024,
      2048LL * 2048, 1024LL * 2048, 2048LL * 1024);

  // logits = attn_out @ Wout^T + bout  -> f32 d_out
  gemm_bt<2, false, false><<<dim3(250, 64, 1), 256, 0, stream>>>(
      AttnO, WoutB, out, bout, 1024, 1024, 1024, VOCAB, 0, 0, 0);
}

// Round 2
// 995.070 us; speedup vs baseline: 1.1632x; 1.1632x over previous
//
#include <hip/hip_runtime.h>
#include <hip/hip_bf16.h>
#include <cmath>
#include <cstdint>

typedef __bf16 bf16_t;
typedef bf16_t bf16x8 __attribute__((ext_vector_type(8)));
typedef bf16_t bf16x4 __attribute__((ext_vector_type(4)));
typedef float  f32x4  __attribute__((ext_vector_type(4)));

#define VOCAB 32000
#define DDIM  1024
#define BATCH 4
#define SEQ   2048
#define MTOT  (BATCH*SEQ)                       // 8192
#define LOGITS_ELEMS (262144000LL)              // MTOT*VOCAB

// ---- ws layout (bytes) ----
#define WQKV_OFF 0LL                            // [3072][1024] bf16
#define WOUT_OFF 6291456LL                      // [32000][1024] bf16
#define X_OFF    71827456LL                     // [8192][1024] bf16 (reused as attn_out)
#define QKV_OFF  88604672LL                     // [8192][3072] bf16
#define VT_OFF   138936320LL                    // [4][1024][2048] bf16
#define ABF_OFF  155713536LL                    // [4][2048][2048] bf16
// END = 189267968 bytes required in ws

__device__ __forceinline__ void gl_lds16(const void* g, void* l) {
  __builtin_amdgcn_global_load_lds(
      (const __attribute__((address_space(1))) void*)g,
      (__attribute__((address_space(3))) void*)l, 16, 0, 0);
}

// ---------------- f32 -> bf16 convert (vectorized, grid-stride) ----------------
__global__ __launch_bounds__(256)
void cvt_bf16(const float* __restrict__ s, bf16_t* __restrict__ d, int n4) {
  int i = blockIdx.x * 256 + threadIdx.x;
  const int stride = gridDim.x * 256;
  for (; i < n4; i += stride) {
    float4 v = ((const float4*)s)[i];
    bf16x4 o;
    o[0] = (bf16_t)v.x; o[1] = (bf16_t)v.y; o[2] = (bf16_t)v.z; o[3] = (bf16_t)v.w;
    ((bf16x4*)d)[i] = o;
  }
}

// ---------------- embedding gather + cast ----------------
__global__ __launch_bounds__(256)
void gather_cast(const int* __restrict__ idx, const float* __restrict__ embed,
                 bf16_t* __restrict__ X) {
  const int m = blockIdx.x;
  const int row = idx[m];
  float4 v = ((const float4*)(embed + (long long)row * DDIM))[threadIdx.x];
  bf16x4 o;
  o[0] = (bf16_t)v.x; o[1] = (bf16_t)v.y; o[2] = (bf16_t)v.z; o[3] = (bf16_t)v.w;
  *(bf16x4*)(X + (long long)m * DDIM + threadIdx.x * 4) = o;
}

// ---------------- V transpose: QKV cols[2048..3071] -> Vt[b][d][s] ----------------
__global__ __launch_bounds__(256)
void transpose_v(const bf16_t* __restrict__ QKV, bf16_t* __restrict__ Vt) {
  __shared__ bf16_t tile[64][65];
  const int b = blockIdx.z;
  const int s0 = blockIdx.x * 64, d0 = blockIdx.y * 64;
  const int tx = threadIdx.x & 63, ty = threadIdx.x >> 6;
  #pragma unroll
  for (int i = ty; i < 64; i += 4)
    tile[i][tx] = QKV[((long long)b * SEQ + s0 + i) * 3072 + 2048 + d0 + tx];
  __syncthreads();
  #pragma unroll
  for (int i = ty; i < 64; i += 4)
    Vt[((long long)b * DDIM + d0 + i) * SEQ + s0 + tx] = tile[tx][i];
}

// ---------------- 128x128 BT-GEMM (kept for scores / PV) ----------------
// OMODE: 0 = bf16 out, 1 = f32 out, 2 = f32 out + bias
template<int OMODE, bool CSKIP, bool CTRIM>
__global__ __launch_bounds__(256)
void gemm_bt(const bf16_t* __restrict__ A, const bf16_t* __restrict__ B,
             void* __restrict__ Cv, const float* __restrict__ bias,
             int K, int lda, int ldb, int ldc,
             long long sA, long long sB, long long sC) {
  const int bn = blockIdx.x, bm = blockIdx.y, bz = blockIdx.z;
  if (CSKIP && bn > bm) return;

  __shared__ bf16_t As[128 * 32];
  __shared__ bf16_t Bs[128 * 32];

  const int t = threadIdx.x;
  const int lane = t & 63;
  const int w = t >> 6;
  const int wr = w >> 1, wc = w & 1;

  f32x4 acc[4][4];
  #pragma unroll
  for (int m = 0; m < 4; m++)
    #pragma unroll
    for (int n = 0; n < 4; n++)
      #pragma unroll
      for (int r = 0; r < 4; r++) acc[m][n][r] = 0.f;

  int kEnd = K;
  if (CTRIM) { int ke = (bm + 1) * 128; kEnd = ke < K ? ke : K; }

  const bf16_t* Ab = A + (long long)bz * sA + (long long)(bm * 128) * lda;
  const bf16_t* Bb = B + (long long)bz * sB + (long long)(bn * 128) * ldb;

  const int srow = t >> 2;
  const int scol = (t & 3) * 8;

  const int fr = lane & 15;
  const int fq = lane >> 4;
  const int aoff0 = (wr * 64 + fr) * 32 + fq * 8;
  const int boff0 = (wc * 64 + fr) * 32 + fq * 8;

  for (int k0 = 0; k0 < kEnd; k0 += 32) {
    gl_lds16(Ab + (long long)srow * lda + k0 + scol, &As[t * 8]);
    gl_lds16(Ab + (long long)(srow + 64) * lda + k0 + scol, &As[2048 + t * 8]);
    gl_lds16(Bb + (long long)srow * ldb + k0 + scol, &Bs[t * 8]);
    gl_lds16(Bb + (long long)(srow + 64) * ldb + k0 + scol, &Bs[2048 + t * 8]);
    __syncthreads();

    bf16x8 af[4], bv[4];
    #pragma unroll
    for (int m = 0; m < 4; m++) af[m] = *(const bf16x8*)&As[aoff0 + m * 16 * 32];
    #pragma unroll
    for (int n = 0; n < 4; n++) bv[n] = *(const bf16x8*)&Bs[boff0 + n * 16 * 32];
    #pragma unroll
    for (int m = 0; m < 4; m++)
      #pragma unroll
      for (int n = 0; n < 4; n++)
        acc[m][n] = __builtin_amdgcn_mfma_f32_16x16x32_bf16(af[m], bv[n], acc[m][n], 0, 0, 0);
    __syncthreads();
  }

  const long long cb = (long long)bz * sC;
  const int row0 = bm * 128 + wr * 64 + fq * 4;
  const int col0 = bn * 128 + wc * 64 + fr;
  #pragma unroll
  for (int m = 0; m < 4; m++)
    #pragma unroll
    for (int n = 0; n < 4; n++) {
      const int col = col0 + n * 16;
      const float bvs = (OMODE == 2) ? bias[col] : 0.f;
      #pragma unroll
      for (int r = 0; r < 4; r++) {
        const int row = row0 + m * 16 + r;
        const float v = acc[m][n][r];
        if (OMODE == 0)
          ((bf16_t*)Cv)[cb + (long long)row * ldc + col] = (bf16_t)v;
        else
          ((float*)Cv)[cb + (long long)row * ldc + col] = v + bvs;
      }
    }
}

// ---------------- 256x256 8-phase pipelined BT-GEMM (T1+T2+T3+T4+T5) ----------------
// C[m,n] = sum_k A[m,k]*B[n,k].  Requires M%256==0, N%256==0, K%64==0, K>=128.
// LDS: 2 buffers x 4 half-tiles (A0,A1,B0,B1) x [128 rows][64 cols] bf16 = 128 KiB.
// Swizzle: logical (row,c16) stored at physical c16^(row&7) (16B granule) via
// pre-swizzled global source + linear global_load_lds dest (rule 21).
// Schedule per K-tile t (phases = C quadrants q00,q01,q11,q10):
//   ph0: read A0,B0 frags; stage (t+1).B0   ph1: read B1; stage (t+2).A0
//   ph2: read A1;          stage (t+2).B1   ph3: read B0; stage (t+2).A1
// Each staged slot's last LDS reader finished the previous phase (lgkmcnt(0)
// precedes that phase's closing barrier). Steady-state boundary wait vmcnt(6)
// (= 3 half-tiles in flight); drains to 0 before the last tile.
#define STAGE(buf, h, src, ld, k0) do {                                   \
    gl_lds16((src) + (k0), &lds[buf][h][tt * 8]);                         \
    gl_lds16((src) + (long long)64 * (ld) + (k0), &lds[buf][h][4096 + tt * 8]); \
  } while (0)

#define LDA_FRAGS(buf, qm)                                                \
  _Pragma("unroll") for (int m_ = 0; m_ < 4; ++m_)                        \
  _Pragma("unroll") for (int ks_ = 0; ks_ < 2; ++ks_)                     \
    af[ks_][m_] = *(const bf16x8*)&lds[buf][qm][offA[m_][ks_]];

#define LDB_FRAGS(buf, qn)                                                \
  _Pragma("unroll") for (int n_ = 0; n_ < 2; ++n_)                        \
  _Pragma("unroll") for (int ks_ = 0; ks_ < 2; ++ks_)                     \
    bv[ks_][n_] = *(const bf16x8*)&lds[buf][2 + (qn)][offB[n_][ks_]];

#define MFMA_Q(qm, qn)                                                    \
  _Pragma("unroll") for (int m_ = 0; m_ < 4; ++m_)                        \
  _Pragma("unroll") for (int n_ = 0; n_ < 2; ++n_)                        \
  _Pragma("unroll") for (int ks_ = 0; ks_ < 2; ++ks_)                     \
    acc[qm][qn][m_][n_] = __builtin_amdgcn_mfma_f32_16x16x32_bf16(        \
        af[ks_][m_], bv[ks_][n_], acc[qm][qn][m_][n_], 0, 0, 0);

#define PHASE_MID() do {                                                  \
    __builtin_amdgcn_s_barrier();                                         \
    asm volatile("s_waitcnt lgkmcnt(0)" ::: "memory");                    \
    __builtin_amdgcn_sched_barrier(0);                                    \
    __builtin_amdgcn_s_setprio(1);                                        \
  } while (0)

#define PHASE_END() do {                                                  \
    __builtin_amdgcn_s_setprio(0);                                        \
    asm volatile("" ::: "memory");                                        \
    __builtin_amdgcn_s_barrier();                                         \
  } while (0)

template<int OMODE>   // 0 = bf16 out, 2 = f32 out + bias
__global__ __launch_bounds__(512, 2)
void gemm256(const bf16_t* __restrict__ A, const bf16_t* __restrict__ B,
             void* __restrict__ Cv, const float* __restrict__ bias,
             int K, int lda, int ldb, int ldc, int nbm) {
  __shared__ bf16_t lds[2][4][8192];

  // T1: bijective XCD swizzle (grid % 8 == 0 at all call sites)
  const int nwg = gridDim.x;
  const int bid = blockIdx.x;
  const int swz = (nwg & 7) ? bid : ((bid & 7) * (nwg >> 3) + (bid >> 3));
  const int bm = swz % nbm;
  const int bn = swz / nbm;

  const int tt = threadIdx.x;
  const int lane = tt & 63;
  const int w = tt >> 6;
  const int wr = w >> 2, wc = w & 3;
  const int fr = lane & 15, fq = lane >> 4;

  // staging source (pre-swizzled so linear LDS dest holds swizzled layout)
  const int srow = tt >> 3;                    // 0..63
  const int cl = (tt & 7) ^ (srow & 7);        // (64+srow)&7 == srow&7
  const bf16_t* sA0 = A + (long long)(bm * 256 +       srow) * lda + cl * 8;
  const bf16_t* sA1 = A + (long long)(bm * 256 + 128 + srow) * lda + cl * 8;
  const bf16_t* sB0 = B + (long long)(bn * 256 +       srow) * ldb + cl * 8;
  const bf16_t* sB1 = B + (long long)(bn * 256 + 128 + srow) * ldb + cl * 8;

  // swizzled LDS read offsets (elements)
  int offA[4][2], offB[2][2];
  #pragma unroll
  for (int m = 0; m < 4; ++m)
    #pragma unroll
    for (int ks = 0; ks < 2; ++ks) {
      const int r = wr * 64 + m * 16 + fr;
      offA[m][ks] = r * 64 + (((ks * 4 + fq) ^ (r & 7)) * 8);
    }
  #pragma unroll
  for (int n = 0; n < 2; ++n)
    #pragma unroll
    for (int ks = 0; ks < 2; ++ks) {
      const int r = wc * 32 + n * 16 + fr;
      offB[n][ks] = r * 64 + (((ks * 4 + fq) ^ (r & 7)) * 8);
    }

  f32x4 acc[2][2][4][2];
  #pragma unroll
  for (int i = 0; i < 2; ++i)
    #pragma unroll
    for (int j = 0; j < 2; ++j)
      #pragma unroll
      for (int m = 0; m < 4; ++m)
        #pragma unroll
        for (int n = 0; n < 2; ++n)
          #pragma unroll
          for (int r = 0; r < 4; ++r) acc[i][j][m][n][r] = 0.f;

  bf16x8 af[2][4], bv[2][2];
  const int NT = K >> 6;

  // prologue: tile0 complete + tile1 {A0,B1,A1} (B0 arrives at PH(0,0))
  STAGE(0, 0, sA0, lda, 0); STAGE(0, 1, sA1, lda, 0);
  STAGE(0, 2, sB0, ldb, 0); STAGE(0, 3, sB1, ldb, 0);
  STAGE(1, 0, sA0, lda, 64); STAGE(1, 3, sB1, ldb, 64); STAGE(1, 1, sA1, lda, 64);
  asm volatile("s_waitcnt vmcnt(6)" ::: "memory");
  __builtin_amdgcn_s_barrier();

  int b = 0;
  for (int t = 0; t < NT; ++t, b ^= 1) {
    const int nb = b ^ 1;
    const long long k1 = (long long)(t + 1) << 6;
    const long long k2 = (long long)(t + 2) << 6;

    // phase 0: quadrant (0,0)
    LDA_FRAGS(b, 0)
    LDB_FRAGS(b, 0)
    if (t + 1 < NT) STAGE(nb, 2, sB0, ldb, k1);
    PHASE_MID();
    MFMA_Q(0, 0)
    PHASE_END();

    // phase 1: quadrant (0,1) — reuse af
    LDB_FRAGS(b, 1)
    if (t + 2 < NT) STAGE(b, 0, sA0, lda, k2);
    PHASE_MID();
    MFMA_Q(0, 1)
    PHASE_END();

    // phase 2: quadrant (1,1) — reuse bv
    LDA_FRAGS(b, 1)
    if (t + 2 < NT) STAGE(b, 3, sB1, ldb, k2);
    PHASE_MID();
    MFMA_Q(1, 1)
    PHASE_END();

    // phase 3: quadrant (1,0)
    LDB_FRAGS(b, 0)
    if (t + 2 < NT) STAGE(b, 1, sA1, lda, k2);
    PHASE_MID();
    MFMA_Q(1, 0)
    __builtin_amdgcn_s_setprio(0);
    if (t < NT - 1) {
      if (t <= NT - 3) asm volatile("s_waitcnt vmcnt(6)" ::: "memory");
      else             asm volatile("s_waitcnt vmcnt(0)" ::: "memory");
    }
    asm volatile("" ::: "memory");
    __builtin_amdgcn_s_barrier();
  }

  // epilogue
  #pragma unroll
  for (int qm = 0; qm < 2; ++qm)
    #pragma unroll
    for (int qn = 0; qn < 2; ++qn)
      #pragma unroll
      for (int m = 0; m < 4; ++m)
        #pragma unroll
        for (int n = 0; n < 2; ++n) {
          const int row0 = bm * 256 + qm * 128 + wr * 64 + m * 16 + fq * 4;
          const int col  = bn * 256 + qn * 128 + wc * 32 + n * 16 + fr;
          const float bb = (OMODE == 2) ? bias[col] : 0.f;
          #pragma unroll
          for (int r = 0; r < 4; ++r) {
            const float v = acc[qm][qn][m][n][r] + bb;
            if (OMODE == 0)
              ((bf16_t*)Cv)[(long long)(row0 + r) * ldc + col] = (bf16_t)v;
            else
              ((float*)Cv)[(long long)(row0 + r) * ldc + col] = v;
          }
        }
}

// ---------------- row softmax with causal mask ----------------
__device__ __forceinline__ float wred_max(float v) {
  #pragma unroll
  for (int o = 32; o; o >>= 1) v = fmaxf(v, __shfl_xor(v, o, 64));
  return v;
}
__device__ __forceinline__ float wred_sum(float v) {
  #pragma unroll
  for (int o = 32; o; o >>= 1) v += __shfl_xor(v, o, 64);
  return v;
}

__global__ __launch_bounds__(256)
void softmax_rows(const float* __restrict__ scores, float* __restrict__ Aout,
                  bf16_t* __restrict__ Abf) {
  const int m = blockIdx.x;          // 0..8191
  const int q = m & (SEQ - 1);
  const float* srow = scores + (long long)m * SEQ;
  const int t = threadIdx.x;
  const int base = t * 8;
  const float scale = 0.03125f;      // 1/sqrt(1024)

  float4 a = ((const float4*)srow)[t * 2];
  float4 b = ((const float4*)srow)[t * 2 + 1];
  float v[8] = {a.x, a.y, a.z, a.w, b.x, b.y, b.z, b.w};

  float mx = -INFINITY;
  #pragma unroll
  for (int i = 0; i < 8; i++) {
    v[i] = (base + i <= q) ? v[i] * scale : -INFINITY;
    mx = fmaxf(mx, v[i]);
  }
  __shared__ float redm[4], reds[4];
  const int lane = t & 63, w = t >> 6;
  float wm = wred_max(mx);
  if (lane == 0) redm[w] = wm;
  __syncthreads();
  mx = fmaxf(fmaxf(redm[0], redm[1]), fmaxf(redm[2], redm[3]));

  float e[8]; float s = 0.f;
  #pragma unroll
  for (int i = 0; i < 8; i++) {
    e[i] = (base + i <= q) ? __expf(v[i] - mx) : 0.f;
    s += e[i];
  }
  float wsu = wred_sum(s);
  if (lane == 0) reds[w] = wsu;
  __syncthreads();
  s = reds[0] + reds[1] + reds[2] + reds[3];
  const float inv = 1.f / s;

  float4 o0, o1; bf16x8 ob;
  float av[8];
  #pragma unroll
  for (int i = 0; i < 8; i++) { av[i] = e[i] * inv; ob[i] = (bf16_t)av[i]; }
  o0.x = av[0]; o0.y = av[1]; o0.z = av[2]; o0.w = av[3];
  o1.x = av[4]; o1.y = av[5]; o1.z = av[6]; o1.w = av[7];
  float* orow = Aout + (long long)m * SEQ;
  ((float4*)orow)[t * 2] = o0;
  ((float4*)orow)[t * 2 + 1] = o1;
  *(bf16x8*)(Abf + (long long)m * SEQ + base) = ob;
}

// ---------------- launch ----------------
extern "C" void kernel_launch(void* const* d_in, const int* in_sizes, int n_in,
                              void* d_out, int out_size, void* d_ws, size_t ws_size,
                              hipStream_t stream) {
  const int*   idx   = (const int*)d_in[0];
  const float* embed = (const float*)d_in[1];
  const float* Wq    = (const float*)d_in[2];
  const float* Wk    = (const float*)d_in[3];
  const float* Wv    = (const float*)d_in[4];
  const float* Wout  = (const float*)d_in[5];
  const float* bout  = (const float*)d_in[6];

  float* out = (float*)d_out;
  char*  ws  = (char*)d_ws;

  bf16_t* Wqkv  = (bf16_t*)(ws + WQKV_OFF);
  bf16_t* WoutB = (bf16_t*)(ws + WOUT_OFF);
  bf16_t* X     = (bf16_t*)(ws + X_OFF);
  bf16_t* QKV   = (bf16_t*)(ws + QKV_OFF);
  bf16_t* Vt    = (bf16_t*)(ws + VT_OFF);
  bf16_t* Abf   = (bf16_t*)(ws + ABF_OFF);
  bf16_t* AttnO = X;                       // X dead after QKV projection
  float*  scores = out;                    // scratch in (unwritten) logits region
  float*  Aout   = out + LOGITS_ELEMS;

  // weight converts
  cvt_bf16<<<1024, 256, 0, stream>>>(Wq, Wqkv,            262144);
  cvt_bf16<<<1024, 256, 0, stream>>>(Wk, Wqkv + 1048576,  262144);
  cvt_bf16<<<1024, 256, 0, stream>>>(Wv, Wqkv + 2097152,  262144);
  cvt_bf16<<<4096, 256, 0, stream>>>(Wout, WoutB,         8192000);

  // x = embed[idx] (bf16)
  gather_cast<<<8192, 256, 0, stream>>>(idx, embed, X);

  // QKV = X @ Wqkv^T  -> [8192][3072] bf16   (256² 8-phase, grid 32x12=384)
  gemm256<0><<<dim3(384), 512, 0, stream>>>(
      X, Wqkv, QKV, nullptr, 1024, 1024, 1024, 3072, 32);

  // Vt[b][d][s]
  transpose_v<<<dim3(32, 16, 4), 256, 0, stream>>>(QKV, Vt);

  // scores[b][q][k] = Q.K^T (unscaled), lower-triangle tiles only
  gemm_bt<1, true, false><<<dim3(16, 16, 4), 256, 0, stream>>>(
      QKV, QKV + 1024, scores, nullptr, 1024, 3072, 3072, 2048,
      2048LL * 3072, 2048LL * 3072, 2048LL * 2048);

  // A = softmax(scores/32) with causal mask; writes f32 to d_out + bf16 to ws
  softmax_rows<<<8192, 256, 0, stream>>>(scores, Aout, Abf);

  // attn_out = A @ V   (K trimmed to causal extent)
  gemm_bt<0, false, true><<<dim3(8, 16, 4), 256, 0, stream>>>(
      Abf, Vt, AttnO, nullptr, 2048, 2048, 2048, 1024,
      2048LL * 2048, 1024LL * 2048, 2048LL * 1024);

  // logits = attn_out @ Wout^T + bout  (256² 8-phase, grid 32x125=4000)
  gemm256<2><<<dim3(4000), 512, 0, stream>>>(
      AttnO, WoutB, out, bout, 1024, 1024, 1024, VOCAB, 32);
}